// Round 4
// baseline (246.007 us; speedup 1.0000x reference)
//
#include <hip/hip_runtime.h>

// Problem constants
#define IN_CAPS  1152
#define IN_DIM   8
#define NUM_CAPS 10
#define DIM_CAPS 16
#define B_TOT    256

// routing-pass tiling: 1536 blocks = 8 XCD chunks x 24 i-tiles x 8 b-blocks
// I_T=6 doubles wave count vs I_T=12 -> 6 waves/SIMD (VGPR=72 caps at 7).
#define I_T     6                  // i's per block -> 192 i-tiles
#define P_TILES (IN_CAPS / I_T)    // 192
#define B_BLK   32                 // batches per block: 4 waves x (4 bsub x 2)

// ws layout (floats):
//   Vbuf  [256][10][16]        = 40960
//   spart [192][256][10][16]   = 7864320  (~31.5 MB)
//   Wt2   [1152][10][16][8]    = 1474560  (i, n, d, k) -- d on lanes
#define VBUF_F  (B_TOT * NUM_CAPS * DIM_CAPS)
#define SPART_F (P_TILES * B_TOT * NUM_CAPS * DIM_CAPS)

// ---- 16-lane (d) sum reduction, pure VALU via DPP row ops (no LDS) ----
template <int CTRL>
__device__ __forceinline__ float dpp_add16(float v) {
  int p = __builtin_amdgcn_update_dpp(0, __float_as_int(v), CTRL, 0xF, 0xF, true);
  return v + __int_as_float(p);
}
__device__ __forceinline__ float red16(float v) {
  v = dpp_add16<0xB1>(v);   // quad_perm [1,0,3,2]  : xor 1
  v = dpp_add16<0x4E>(v);   // quad_perm [2,3,0,1]  : xor 2
  v = dpp_add16<0x141>(v);  // row_half_mirror
  v = dpp_add16<0x140>(v);  // row_mirror
  return v;                 // all 16 lanes hold the d-sum
}

// Transpose W[0][n][i][d][k8] -> Wt2[i][n][d][k8]: per (i,n) the 16 d-lanes
// read/write 512B contiguous.
__global__ __launch_bounds__(320) void transpose2_kernel(
    const float* __restrict__ W, float* __restrict__ Wt) {
  const int i = blockIdx.x;
  const int t = threadIdx.x;       // 320 = 10n * 16d * 2h
  const int d = t & 15;
  const int h = (t >> 4) & 1;
  const int n = t >> 5;            // 0..9
  const float4* Wf4 = (const float4*)W;
  float4* Wtf4 = (float4*)Wt;
  float4 v = Wf4[(((size_t)n * IN_CAPS + i) * DIM_CAPS + d) * 2 + h];
  Wtf4[(((size_t)i * NUM_CAPS + n) * DIM_CAPS + d) * 2 + h] = v;
}

// One routing pass, recomputing u_hat from L2-resident x + Wt2.
// Lane mapping: d = lane&15 (full 64-lane utilization, no masking).
// Each thread: 2 batches (ba, bb=ba+4); wave: 8 batches x 16 d.
// bd = u.V reduced over d via DPP; softmax over n=10 in-register.
// ZERO_V=1 (pass 0): V==0 -> c = 1/10 exactly; no softmax at all.
template <int ZERO_V>
__global__ __launch_bounds__(256) void route3_kernel(
    const float* __restrict__ x, const float* __restrict__ Wt,
    const float* __restrict__ Vbuf, float* __restrict__ spart) {
  const int tid  = threadIdx.x;
  const int d    = tid & 15;
  const int bsub = (tid >> 4) & 3;
  const int w    = tid >> 6;          // wave 0..3

  const int lid  = blockIdx.x;        // 0..1535
  const int xcd  = lid & 7;
  const int r    = lid >> 3;          // 0..191
  const int tile = xcd * 24 + (r % 24);
  const int bblk = r / 24;            // 0..7
  const int i0   = tile * I_T;
  const int ba   = bblk * B_BLK + w * 8 + bsub;  // first batch
  const int bb   = ba + 4;                        // second batch

  float Va[NUM_CAPS], Vb[NUM_CAPS];
  if (!ZERO_V) {
#pragma unroll
    for (int n = 0; n < NUM_CAPS; ++n) {
      Va[n] = Vbuf[((size_t)ba * NUM_CAPS + n) * DIM_CAPS + d];
      Vb[n] = Vbuf[((size_t)bb * NUM_CAPS + n) * DIM_CAPS + d];
    }
  }

  float sa[NUM_CAPS], sb[NUM_CAPS];
#pragma unroll
  for (int n = 0; n < NUM_CAPS; ++n) { sa[n] = 0.f; sb[n] = 0.f; }

  const float4* __restrict__ Wtp = (const float4*)Wt;
  const float4* __restrict__ xp  = (const float4*)x;

  for (int i = i0; i < i0 + I_T; ++i) {
    float4 xa0 = xp[(size_t)(ba * IN_CAPS + i) * 2];
    float4 xa1 = xp[(size_t)(ba * IN_CAPS + i) * 2 + 1];
    float4 xb0 = xp[(size_t)(bb * IN_CAPS + i) * 2];
    float4 xb1 = xp[(size_t)(bb * IN_CAPS + i) * 2 + 1];

    // W base for this (i, d): float4 index ((i*10 + n)*16 + d)*2 + h
    const float4* wb = Wtp + ((size_t)i * NUM_CAPS * DIM_CAPS + d) * 2;

    float ua[NUM_CAPS], ub[NUM_CAPS];
#pragma unroll
    for (int n = 0; n < NUM_CAPS; ++n) {
      float4 w0 = wb[n * (DIM_CAPS * 2)];
      float4 w1 = wb[n * (DIM_CAPS * 2) + 1];
      ua[n] = w0.x * xa0.x + w0.y * xa0.y + w0.z * xa0.z + w0.w * xa0.w
            + w1.x * xa1.x + w1.y * xa1.y + w1.z * xa1.z + w1.w * xa1.w;
      ub[n] = w0.x * xb0.x + w0.y * xb0.y + w0.z * xb0.z + w0.w * xb0.w
            + w1.x * xb1.x + w1.y * xb1.y + w1.z * xb1.z + w1.w * xb1.w;
    }

    if (ZERO_V) {
#pragma unroll
      for (int n = 0; n < NUM_CAPS; ++n) { sa[n] += ua[n]; sb[n] += ub[n]; }
    } else {
      float ea[NUM_CAPS], eb[NUM_CAPS];
      float esa = 0.f, esb = 0.f;
#pragma unroll
      for (int n = 0; n < NUM_CAPS; ++n) {
        ea[n] = __expf(red16(ua[n] * Va[n]));
        eb[n] = __expf(red16(ub[n] * Vb[n]));
        esa += ea[n];
        esb += eb[n];
      }
      float ra = 1.f / esa, rb = 1.f / esb;
#pragma unroll
      for (int n = 0; n < NUM_CAPS; ++n) {
        sa[n] += (ea[n] * ra) * ua[n];
        sb[n] += (eb[n] * rb) * ub[n];
      }
    }
  }

  // spart[tile][b][n][d]; 16 d-lanes write 64B contiguous per (b,n)
  float* spa = spart + ((size_t)(tile * B_TOT + ba) * NUM_CAPS) * DIM_CAPS + d;
  float* spb = spart + ((size_t)(tile * B_TOT + bb) * NUM_CAPS) * DIM_CAPS + d;
  const float cs = ZERO_V ? 0.1f : 1.f;
#pragma unroll
  for (int n = 0; n < NUM_CAPS; ++n) {
    spa[n * DIM_CAPS] = cs * sa[n];
    spb[n * DIM_CAPS] = cs * sb[n];
  }
}

// Reduce NT partial tiles -> s; v = squash(s); V += v or out = v.
template <int NT>
__global__ void vupdate_kernel(const float* __restrict__ spart,
                               float* __restrict__ Vbuf,
                               float* __restrict__ out, int is_final) {
  const int b   = blockIdx.x;            // 0..255
  const int t   = threadIdx.x;           // 0..159 : n = t/16, d = t%16
  const int base = b * (NUM_CAPS * DIM_CAPS) + t;
  float s = 0.f;
#pragma unroll 16
  for (int tl = 0; tl < NT; ++tl) {
    s += spart[(size_t)tl * (B_TOT * NUM_CAPS * DIM_CAPS) + base];
  }
  float sq = s * s;
#pragma unroll
  for (int m = 1; m < 16; m <<= 1) sq += __shfl_xor(sq, m, 16);  // sum over d
  float norm = sqrtf(sq);
  float v = s * (sq / (1.f + sq)) / (norm + 1e-8f);
  if (is_final) {
    out[base] = v;
  } else {
    Vbuf[base] += v;
  }
}

extern "C" void kernel_launch(void* const* d_in, const int* in_sizes, int n_in,
                              void* d_out, int out_size, void* d_ws, size_t ws_size,
                              hipStream_t stream) {
  const float* x = (const float*)d_in[0];  // [256,1152,8]
  const float* W = (const float*)d_in[1];  // [1,10,1152,16,8]
  float* out   = (float*)d_out;            // [256,10,16]
  float* Vbuf  = (float*)d_ws;
  float* spart = Vbuf + VBUF_F;
  float* Wt2   = spart + SPART_F;

  (void)hipMemsetAsync(Vbuf, 0, (size_t)VBUF_F * sizeof(float), stream);

  transpose2_kernel<<<IN_CAPS, 320, 0, stream>>>(W, Wt2);

  // pass 0: V == 0 -> c = 0.1 exactly
  route3_kernel<1><<<P_TILES * 8, 256, 0, stream>>>(x, Wt2, Vbuf, spart);
  vupdate_kernel<P_TILES><<<B_TOT, NUM_CAPS * DIM_CAPS, 0, stream>>>(spart, Vbuf, out, 0);

  // passes 1..3
  for (int p = 1; p < 4; ++p) {
    route3_kernel<0><<<P_TILES * 8, 256, 0, stream>>>(x, Wt2, Vbuf, spart);
    vupdate_kernel<P_TILES><<<B_TOT, NUM_CAPS * DIM_CAPS, 0, stream>>>(spart, Vbuf, out, p == 3);
  }
}

// Round 5
// 243.778 us; speedup vs baseline: 1.0091x; 1.0091x over previous
//
#include <hip/hip_runtime.h>
#include <hip/hip_fp16.h>

// Problem constants
#define IN_CAPS  1152
#define NUM_CAPS 10
#define DIM_CAPS 16
#define B_TOT    256

// routing-pass tiling: 768 blocks = 8 XCD chunks x 24 i-tiles x 4 b-blocks
#define I_T     6                  // i's per block -> 192 i-tiles
#define P_TILES (IN_CAPS / I_T)    // 192
#define B_BLK   64                 // batches per block: 4 waves x 16 batches (MFMA M=16)

// ws layout (floats):
//   Vbuf  [256][10][16]        = 40960
//   spart [192][256][10][16]   = 7864320
//   Wh    [1152][10][64] uint4 = 2949120 float-slots (f16 B-fragments, zero-padded k>=8)
#define VBUF_F  (B_TOT * NUM_CAPS * DIM_CAPS)
#define SPART_F (P_TILES * B_TOT * NUM_CAPS * DIM_CAPS)

typedef _Float16 f16x8 __attribute__((ext_vector_type(8)));
typedef float    f32x4 __attribute__((ext_vector_type(4)));

// ---- 16-lane (d) sum reduction, pure VALU via DPP row ops (no LDS) ----
template <int CTRL>
__device__ __forceinline__ float dpp_add16(float v) {
  int p = __builtin_amdgcn_update_dpp(0, __float_as_int(v), CTRL, 0xF, 0xF, true);
  return v + __int_as_float(p);
}
__device__ __forceinline__ float red16(float v) {
  v = dpp_add16<0xB1>(v);   // quad_perm xor1
  v = dpp_add16<0x4E>(v);   // quad_perm xor2
  v = dpp_add16<0x141>(v);  // row_half_mirror
  v = dpp_add16<0x140>(v);  // row_mirror
  return v;                 // all 16 lanes hold the d-sum
}

__device__ __forceinline__ unsigned packh2(float a, float b) {
  __half2 h = __float22half2_rn(make_float2(a, b));
  return *reinterpret_cast<unsigned*>(&h);
}

// W[0][n][i][d][k8] fp32 -> Wh[i][n][lane] : f16 B-fragment for
// mfma_f32_16x16x32_f16 (col = lane&15 = d, k = (lane>>4)*8+e; k>=8 zero).
__global__ __launch_bounds__(640) void transpose_kernel(
    const float* __restrict__ W, uint4* __restrict__ Wh) {
  const int i = blockIdx.x;
  const int t = threadIdx.x;   // 640 = 10 n * 64 lanes
  const int l = t & 63;
  const int n = t >> 6;
  uint4 v = make_uint4(0u, 0u, 0u, 0u);
  if ((l >> 4) == 0) {         // only k-group 0 carries real data (K=8)
    const int d = l & 15;
    const float4* Wf4 = (const float4*)W;
    float4 w0 = Wf4[((size_t)(n * IN_CAPS + i) * DIM_CAPS + d) * 2];
    float4 w1 = Wf4[((size_t)(n * IN_CAPS + i) * DIM_CAPS + d) * 2 + 1];
    v.x = packh2(w0.x, w0.y);  v.y = packh2(w0.z, w0.w);
    v.z = packh2(w1.x, w1.y);  v.w = packh2(w1.z, w1.w);
  }
  Wh[((size_t)i * NUM_CAPS + n) * 64 + l] = v;
}

// One routing pass. u_hat recomputed per i on the (idle) matrix pipe:
// per i, 10x mfma_f32_16x16x32_f16 give u[16 batches][n][16 d] in C-frag
// layout (col=lane&15=d, row=(lane>>4)*4+r = batch) -- exactly the
// d-on-lanes layout the DPP softmax consumes. VALU only does softmax+accum.
// ZERO_V=1 (pass 0): V==0 -> c = 1/10 exactly; no softmax.
template <int ZERO_V>
__global__ __launch_bounds__(256) void route4_kernel(
    const float* __restrict__ x, const uint4* __restrict__ Wh,
    const float* __restrict__ Vbuf, float* __restrict__ spart) {
  const int tid = threadIdx.x;
  const int l   = tid & 63;
  const int w   = tid >> 6;          // wave 0..3
  const int g   = l >> 4;            // k-group / C-row-group
  const int d   = l & 15;            // A-row selector AND C-col (=d)

  const int lid  = blockIdx.x;       // 0..767
  const int xcd  = lid & 7;
  const int r_   = lid >> 3;         // 0..95
  const int tile = xcd * 24 + (r_ % 24);   // 0..191
  const int bblk = r_ / 24;                // 0..3
  const int i0   = tile * I_T;
  const int wb   = bblk * B_BLK + w * 16;  // wave's 16-batch base
  const int bA   = wb + d;                 // batch this lane loads for A (row=l&15)
  const int bC0  = wb + g * 4;             // C rows: bC0 + r, r=0..3

  // V pre-scaled by log2(e) so bd -> exp2 directly (V only feeds bd)
  float V[NUM_CAPS][4];
  if (!ZERO_V) {
#pragma unroll
    for (int n = 0; n < NUM_CAPS; ++n)
#pragma unroll
      for (int r = 0; r < 4; ++r)
        V[n][r] = Vbuf[((size_t)(bC0 + r) * NUM_CAPS + n) * DIM_CAPS + d]
                  * 1.4426950408889634f;
  }

  f32x4 s[NUM_CAPS];
#pragma unroll
  for (int n = 0; n < NUM_CAPS; ++n) s[n] = (f32x4){0.f, 0.f, 0.f, 0.f};

  const float4* __restrict__ xp = (const float4*)x;
  const f32x4 zc = {0.f, 0.f, 0.f, 0.f};

  for (int ii = 0; ii < I_T; ++ii) {
    const int i = i0 + ii;

    // A-fragment: x[bA, i, 0..7] as 8 f16 (k-group 0 only, rest zero)
    float4 xa = xp[(size_t)(bA * IN_CAPS + i) * 2];
    float4 xb = xp[(size_t)(bA * IN_CAPS + i) * 2 + 1];
    uint4 ap;
    ap.x = packh2(xa.x, xa.y);  ap.y = packh2(xa.z, xa.w);
    ap.z = packh2(xb.x, xb.y);  ap.w = packh2(xb.z, xb.w);
    uint4 az = make_uint4(0u, 0u, 0u, 0u);
    uint4 as = (g == 0) ? ap : az;
    f16x8 af = __builtin_bit_cast(f16x8, as);

    const uint4* wp = Wh + ((size_t)i * NUM_CAPS) * 64 + l;

    f32x4 u[NUM_CAPS];
#pragma unroll
    for (int n = 0; n < NUM_CAPS; ++n) {
      f16x8 bf = __builtin_bit_cast(f16x8, wp[n * 64]);
      u[n] = __builtin_amdgcn_mfma_f32_16x16x32_f16(af, bf, zc, 0, 0, 0);
    }

    if (ZERO_V) {
#pragma unroll
      for (int n = 0; n < NUM_CAPS; ++n) s[n] += u[n];
    } else {
      float e[NUM_CAPS][4];
      float es[4] = {0.f, 0.f, 0.f, 0.f};
#pragma unroll
      for (int n = 0; n < NUM_CAPS; ++n) {
#pragma unroll
        for (int r = 0; r < 4; ++r) {
          e[n][r] = exp2f(red16(u[n][r] * V[n][r]));
          es[r] += e[n][r];
        }
      }
      float inv[4];
#pragma unroll
      for (int r = 0; r < 4; ++r) inv[r] = 1.f / es[r];
#pragma unroll
      for (int n = 0; n < NUM_CAPS; ++n)
#pragma unroll
        for (int r = 0; r < 4; ++r)
          s[n][r] += (e[n][r] * inv[r]) * u[n][r];
    }
  }

  // spart[tile][b][n][d]; 16 d-lanes per row-group write 64B contiguous
  const float cs = ZERO_V ? 0.1f : 1.f;
#pragma unroll
  for (int n = 0; n < NUM_CAPS; ++n)
#pragma unroll
    for (int r = 0; r < 4; ++r)
      spart[((size_t)(tile * B_TOT + bC0 + r) * NUM_CAPS + n) * DIM_CAPS + d]
          = cs * s[n][r];
}

// Reduce NT partial tiles -> s; v = squash(s); V += v or out = v.
template <int NT>
__global__ void vupdate_kernel(const float* __restrict__ spart,
                               float* __restrict__ Vbuf,
                               float* __restrict__ out, int is_final) {
  const int b   = blockIdx.x;            // 0..255
  const int t   = threadIdx.x;           // 0..159 : n = t/16, d = t%16
  const int base = b * (NUM_CAPS * DIM_CAPS) + t;
  float s = 0.f;
#pragma unroll 16
  for (int tl = 0; tl < NT; ++tl) {
    s += spart[(size_t)tl * (B_TOT * NUM_CAPS * DIM_CAPS) + base];
  }
  float sq = s * s;
#pragma unroll
  for (int m = 1; m < 16; m <<= 1) sq += __shfl_xor(sq, m, 16);  // sum over d
  float norm = sqrtf(sq);
  float v = s * (sq / (1.f + sq)) / (norm + 1e-8f);
  if (is_final) {
    out[base] = v;
  } else {
    Vbuf[base] += v;
  }
}

extern "C" void kernel_launch(void* const* d_in, const int* in_sizes, int n_in,
                              void* d_out, int out_size, void* d_ws, size_t ws_size,
                              hipStream_t stream) {
  const float* x = (const float*)d_in[0];  // [256,1152,8]
  const float* W = (const float*)d_in[1];  // [1,10,1152,16,8]
  float* out   = (float*)d_out;            // [256,10,16]
  float* Vbuf  = (float*)d_ws;
  float* spart = Vbuf + VBUF_F;
  uint4* Wh    = (uint4*)(spart + SPART_F);

  (void)hipMemsetAsync(Vbuf, 0, (size_t)VBUF_F * sizeof(float), stream);

  transpose_kernel<<<IN_CAPS, 640, 0, stream>>>(W, Wh);

  // pass 0: V == 0 -> c = 0.1 exactly
  route4_kernel<1><<<768, 256, 0, stream>>>(x, Wh, Vbuf, spart);
  vupdate_kernel<P_TILES><<<B_TOT, NUM_CAPS * DIM_CAPS, 0, stream>>>(spart, Vbuf, out, 0);

  // passes 1..3
  for (int p = 1; p < 4; ++p) {
    route4_kernel<0><<<768, 256, 0, stream>>>(x, Wh, Vbuf, spart);
    vupdate_kernel<P_TILES><<<B_TOT, NUM_CAPS * DIM_CAPS, 0, stream>>>(spart, Vbuf, out, p == 3);
  }
}

// Round 6
// 234.002 us; speedup vs baseline: 1.0513x; 1.0418x over previous
//
#include <hip/hip_runtime.h>
#include <hip/hip_fp16.h>

// Problem constants
#define IN_CAPS  1152
#define NUM_CAPS 10
#define DIM_CAPS 16
#define B_TOT    256

// routing-pass tiling: 512 blocks = 8 XCD chunks x 16 i-tiles x 4 b-blocks
// -> exactly 2 blocks/CU resident (VGPR ~190 => 2 waves/SIMD), zero tail.
#define I_T     9                  // i's per block -> 128 i-tiles
#define P_TILES (IN_CAPS / I_T)    // 128
#define B_BLK   64                 // batches per block: 4 waves x 16 (MFMA M=16)

// ws layout (floats):
//   Vbuf  [256][10][16]        = 40960
//   spart [128][256][10][16]   = 5242880
//   Wh    [1152][10][64] uint4 = 2949120 float-slots (f16 B-frags, W dup in k0-7/k8-15)
#define VBUF_F  (B_TOT * NUM_CAPS * DIM_CAPS)
#define SPART_F (P_TILES * B_TOT * NUM_CAPS * DIM_CAPS)

typedef _Float16 f16x8 __attribute__((ext_vector_type(8)));
typedef float    f32x4 __attribute__((ext_vector_type(4)));

// ---- 16-lane (d) sum reduction, pure VALU via DPP row ops (no LDS) ----
template <int CTRL>
__device__ __forceinline__ float dpp_add16(float v) {
  int p = __builtin_amdgcn_update_dpp(0, __float_as_int(v), CTRL, 0xF, 0xF, true);
  return v + __int_as_float(p);
}
__device__ __forceinline__ float red16(float v) {
  v = dpp_add16<0xB1>(v);   // quad_perm xor1
  v = dpp_add16<0x4E>(v);   // quad_perm xor2
  v = dpp_add16<0x141>(v);  // row_half_mirror
  v = dpp_add16<0x140>(v);  // row_mirror
  return v;                 // all 16 lanes hold the d-sum
}

__device__ __forceinline__ unsigned packh2(float a, float b) {
  __half2 h = __float22half2_rn(make_float2(a, b));
  return *reinterpret_cast<unsigned*>(&h);
}

// split x into f16 hi + f16 lo (residual) so one MFMA (k0-7=hi, k8-15=lo with
// W duplicated) accumulates x*W at ~fp32 accuracy.
__device__ __forceinline__ void split2(float a, float b, unsigned& hi, unsigned& lo) {
  __half2 h = __float22half2_rn(make_float2(a, b));
  float2 f = __half22float2(h);
  __half2 l2 = __float22half2_rn(make_float2(a - f.x, b - f.y));
  hi = *reinterpret_cast<unsigned*>(&h);
  lo = *reinterpret_cast<unsigned*>(&l2);
}

// W[0][n][i][d][k8] fp32 -> Wh[i][n][lane] : f16 B-fragment for
// mfma_f32_16x16x32_f16. col=lane&15=d; k-groups 0 AND 1 both carry W[d][0..7]
// (k8-15 multiplies the x_lo residual); k>=16 zero.
__global__ __launch_bounds__(640) void transpose_kernel(
    const float* __restrict__ W, uint4* __restrict__ Wh) {
  const int i = blockIdx.x;
  const int t = threadIdx.x;   // 640 = 10 n * 64 lanes
  const int l = t & 63;
  const int n = t >> 6;
  uint4 v = make_uint4(0u, 0u, 0u, 0u);
  if ((l >> 4) <= 1) {
    const int d = l & 15;
    const float4* Wf4 = (const float4*)W;
    float4 w0 = Wf4[((size_t)(n * IN_CAPS + i) * DIM_CAPS + d) * 2];
    float4 w1 = Wf4[((size_t)(n * IN_CAPS + i) * DIM_CAPS + d) * 2 + 1];
    v.x = packh2(w0.x, w0.y);  v.y = packh2(w0.z, w0.w);
    v.z = packh2(w1.x, w1.y);  v.w = packh2(w1.z, w1.w);
  }
  Wh[((size_t)i * NUM_CAPS + n) * 64 + l] = v;
}

// One routing pass. W fragments staged block-wide through double-buffered LDS
// (10 KB/i): 3 coalesced uint4 loads/thread replace 40 per-lane wave loads, and
// the full compute phase hides the L2 latency. Single barrier per iteration.
// u_hat on the matrix pipe; DPP softmax over d; s accumulated in registers.
template <int ZERO_V>
__global__ __launch_bounds__(256) void route6_kernel(
    const float* __restrict__ x, const uint4* __restrict__ Wh,
    const float* __restrict__ Vbuf, float* __restrict__ spart) {
  __shared__ uint4 sbuf[2][NUM_CAPS * 64];   // 2 x 10 KB

  const int tid = threadIdx.x;
  const int l   = tid & 63;
  const int w   = tid >> 6;          // wave 0..3
  const int g   = l >> 4;            // k-group / C-row-group
  const int d   = l & 15;            // A-row selector AND C-col (=d)

  const int lid  = blockIdx.x;       // 0..511
  const int xcd  = lid & 7;
  const int r_   = lid >> 3;         // 0..63
  const int tile = xcd * 16 + (r_ & 15);   // 0..127
  const int bblk = r_ >> 4;                // 0..3
  const int i0   = tile * I_T;
  const int wb   = bblk * B_BLK + w * 16;  // wave's 16-batch base
  const int bA   = wb + d;                 // batch this lane loads for A
  const int bC0  = wb + g * 4;             // C rows: bC0 + r, r=0..3

  float V[NUM_CAPS][4];
  if (!ZERO_V) {
#pragma unroll
    for (int n = 0; n < NUM_CAPS; ++n)
#pragma unroll
      for (int r = 0; r < 4; ++r)
        V[n][r] = Vbuf[((size_t)(bC0 + r) * NUM_CAPS + n) * DIM_CAPS + d];
  }

  f32x4 s[NUM_CAPS];
#pragma unroll
  for (int n = 0; n < NUM_CAPS; ++n) s[n] = (f32x4){0.f, 0.f, 0.f, 0.f};

  const uint4* Whg = Wh + (size_t)i0 * (NUM_CAPS * 64);
  const float4* xp = (const float4*)x;

  // prologue: stage i0 into sbuf[0], prefetch x(i0)
  {
    uint4 r0 = Whg[tid];
    uint4 r1 = Whg[256 + tid];
    uint4 r2 = make_uint4(0u, 0u, 0u, 0u);
    if (tid < 128) r2 = Whg[512 + tid];
    sbuf[0][tid] = r0;
    sbuf[0][256 + tid] = r1;
    if (tid < 128) sbuf[0][512 + tid] = r2;
  }
  float4 xa = xp[(size_t)(bA * IN_CAPS + i0) * 2];
  float4 xb = xp[(size_t)(bA * IN_CAPS + i0) * 2 + 1];
  __syncthreads();

  const f32x4 zc = {0.f, 0.f, 0.f, 0.f};
  const uint4 z4 = make_uint4(0u, 0u, 0u, 0u);

  for (int ii = 0; ii < I_T; ++ii) {
    const int cur  = ii & 1;
    const bool more = (ii + 1 < I_T);   // uniform
    uint4 p0, p1, p2;
    float4 xan, xbn;
    if (more) {   // issue next-i loads; consumed at bottom -> latency hidden
      const uint4* Whn = Whg + (size_t)(ii + 1) * (NUM_CAPS * 64);
      p0 = Whn[tid];
      p1 = Whn[256 + tid];
      if (tid < 128) p2 = Whn[512 + tid];
      xan = xp[(size_t)(bA * IN_CAPS + (i0 + ii + 1)) * 2];
      xbn = xp[(size_t)(bA * IN_CAPS + (i0 + ii + 1)) * 2 + 1];
    }

    // A-fragment: k0-7 = f16(x) hi, k8-15 = residual lo, k>=16 zero
    uint4 ah, al;
    split2(xa.x, xa.y, ah.x, al.x);
    split2(xa.z, xa.w, ah.y, al.y);
    split2(xb.x, xb.y, ah.z, al.z);
    split2(xb.z, xb.w, ah.w, al.w);
    uint4 as = (g == 0) ? ah : ((g == 1) ? al : z4);
    f16x8 af = __builtin_bit_cast(f16x8, as);

    const uint4* sb = sbuf[cur];
    f32x4 u[NUM_CAPS];
#pragma unroll
    for (int n = 0; n < NUM_CAPS; ++n) {
      f16x8 bf = __builtin_bit_cast(f16x8, sb[n * 64 + l]);   // ds_read_b128
      u[n] = __builtin_amdgcn_mfma_f32_16x16x32_f16(af, bf, zc, 0, 0, 0);
    }

    if (ZERO_V) {
#pragma unroll
      for (int n = 0; n < NUM_CAPS; ++n) s[n] += u[n];
    } else {
      float e[NUM_CAPS][4];
      float es[4] = {0.f, 0.f, 0.f, 0.f};
#pragma unroll
      for (int n = 0; n < NUM_CAPS; ++n)
#pragma unroll
        for (int r = 0; r < 4; ++r) {
          e[n][r] = __expf(red16(u[n][r] * V[n][r]));
          es[r] += e[n][r];
        }
      float inv[4];
#pragma unroll
      for (int r = 0; r < 4; ++r) inv[r] = 1.f / es[r];
#pragma unroll
      for (int n = 0; n < NUM_CAPS; ++n)
#pragma unroll
        for (int r = 0; r < 4; ++r)
          s[n][r] += (e[n][r] * inv[r]) * u[n][r];
    }

    if (more) {
      // write next buffer; safe: all waves passed previous iter's barrier,
      // which is after their reads of this buffer.
      uint4* nb = sbuf[cur ^ 1];
      nb[tid] = p0;
      nb[256 + tid] = p1;
      if (tid < 128) nb[512 + tid] = p2;
      xa = xan; xb = xbn;
      __syncthreads();
    }
  }

  // spart[tile][b][n][d]; 16 d-lanes per row-group write 64B contiguous
  const float cs = ZERO_V ? 0.1f : 1.f;
#pragma unroll
  for (int n = 0; n < NUM_CAPS; ++n)
#pragma unroll
    for (int r = 0; r < 4; ++r)
      spart[((size_t)(tile * B_TOT + bC0 + r) * NUM_CAPS + n) * DIM_CAPS + d]
          = cs * s[n][r];
}

// Reduce NT partial tiles -> s; v = squash(s); V += v or out = v.
template <int NT>
__global__ void vupdate_kernel(const float* __restrict__ spart,
                               float* __restrict__ Vbuf,
                               float* __restrict__ out, int is_final) {
  const int b   = blockIdx.x;            // 0..255
  const int t   = threadIdx.x;           // 0..159 : n = t/16, d = t%16
  const int base = b * (NUM_CAPS * DIM_CAPS) + t;
  float s = 0.f;
#pragma unroll 16
  for (int tl = 0; tl < NT; ++tl) {
    s += spart[(size_t)tl * (B_TOT * NUM_CAPS * DIM_CAPS) + base];
  }
  float sq = s * s;
#pragma unroll
  for (int m = 1; m < 16; m <<= 1) sq += __shfl_xor(sq, m, 16);  // sum over d
  float norm = sqrtf(sq);
  float v = s * (sq / (1.f + sq)) / (norm + 1e-8f);
  if (is_final) {
    out[base] = v;
  } else {
    Vbuf[base] += v;
  }
}

extern "C" void kernel_launch(void* const* d_in, const int* in_sizes, int n_in,
                              void* d_out, int out_size, void* d_ws, size_t ws_size,
                              hipStream_t stream) {
  const float* x = (const float*)d_in[0];  // [256,1152,8]
  const float* W = (const float*)d_in[1];  // [1,10,1152,16,8]
  float* out   = (float*)d_out;            // [256,10,16]
  float* Vbuf  = (float*)d_ws;
  float* spart = Vbuf + VBUF_F;
  uint4* Wh    = (uint4*)(spart + SPART_F);

  (void)hipMemsetAsync(Vbuf, 0, (size_t)VBUF_F * sizeof(float), stream);

  transpose_kernel<<<IN_CAPS, 640, 0, stream>>>(W, Wh);

  // pass 0: V == 0 -> c = 0.1 exactly
  route6_kernel<1><<<512, 256, 0, stream>>>(x, Wh, Vbuf, spart);
  vupdate_kernel<P_TILES><<<B_TOT, NUM_CAPS * DIM_CAPS, 0, stream>>>(spart, Vbuf, out, 0);

  // passes 1..3
  for (int p = 1; p < 4; ++p) {
    route6_kernel<0><<<512, 256, 0, stream>>>(x, Wh, Vbuf, spart);
    vupdate_kernel<P_TILES><<<B_TOT, NUM_CAPS * DIM_CAPS, 0, stream>>>(spart, Vbuf, out, p == 3);
  }
}